// Round 6
// baseline (1205.188 us; speedup 1.0000x reference)
//
#include <hip/hip_runtime.h>

#define NTOK 16384
#define HDIM 2048
#define HD4  512
#define NG   4
#define EPG  16
#define NE   64
#define KSPLIT 4

// ---------------------------------------------------------------------------
// Kernel 1: h = gelu_exact(x @ Wc1 + bc1)   [16384x2048] @ [2048x512]
// v2: LDS-pressure relief. BM=64, BN=128, BK=16, 256 threads, 4x8 microtile.
//  - A (x) staged in LDS, double-buffered, ONE barrier/tile, prefetch issued
//    before the barrier so HBM latency hides under compute (T14 pattern).
//  - B (Wc1, 4MB, L1/L2-resident) read DIRECTLY from global in the inner
//    loop -> LDS pipe only carries A (1 broadcast ds_read_b128/k-step).
//    Model: VALU 32 per-CU-cyc/k-step vs LDS ~12 -> VALU-bound (was 32:57).
//  - grid (256,4) = 1024 blocks = 4 blocks/CU (was 2).
// ---------------------------------------------------------------------------
__global__ __launch_bounds__(256) void gemm_conf_kernel(
    const float* __restrict__ x, const float* __restrict__ Wc1,
    const float* __restrict__ bc1, float* __restrict__ h)
{
    __shared__ float As[2][16][68];   // [buf][kk][row], 64 rows + pad
    const int tid = threadIdx.x;
    const int bm = blockIdx.x;        // 0..255 (64-row stripes)
    const int bn = blockIdx.y;        // 0..3   (128-col stripes)
    const int tr = tid >> 4;          // 0..15 -> rows tr*4 .. tr*4+3
    const int tc = tid & 15;          // 0..15 -> cols tc*8 .. tc*8+7

    float acc[4][8];
#pragma unroll
    for (int i = 0; i < 4; ++i)
#pragma unroll
        for (int j = 0; j < 8; ++j) acc[i][j] = 0.0f;

    // A staging: 64 rows x 16 k = 256 float4, one per thread
    const int arow = tid >> 2;        // 0..63
    const int ak4  = tid & 3;         // 0..3 -> k quad
    const float* xrow = x + (size_t)(bm * 64 + arow) * HDIM + ak4 * 4;

    // B: per-thread column base into Wc1 (row stride HD4)
    const float* wb = Wc1 + bn * 128 + tc * 8;

    float4 va = *(const float4*)(xrow);     // tile 0 prefetch
    int cur = 0;

    for (int k0 = 0; k0 < HDIM; k0 += 16) {
        // write current tile's A into As[cur]
        As[cur][ak4 * 4 + 0][arow] = va.x;
        As[cur][ak4 * 4 + 1][arow] = va.y;
        As[cur][ak4 * 4 + 2][arow] = va.z;
        As[cur][ak4 * 4 + 3][arow] = va.w;
        // issue next tile's global load BEFORE the barrier (hides under compute)
        if (k0 + 16 < HDIM) va = *(const float4*)(xrow + k0 + 16);
        __syncthreads();

        const float* wk = wb + (size_t)k0 * HD4;
#pragma unroll
        for (int kk = 0; kk < 16; ++kk) {
            float4 b0 = *(const float4*)(wk);
            float4 b1 = *(const float4*)(wk + 4);
            wk += HD4;
            float4 a4 = *(const float4*)&As[cur][kk][tr * 4];
            float av[4] = {a4.x, a4.y, a4.z, a4.w};
            float bv[8] = {b0.x, b0.y, b0.z, b0.w, b1.x, b1.y, b1.z, b1.w};
#pragma unroll
            for (int i = 0; i < 4; ++i)
#pragma unroll
                for (int j = 0; j < 8; ++j)
                    acc[i][j] = fmaf(av[i], bv[j], acc[i][j]);
        }
        cur ^= 1;
        // no second barrier needed: next iteration writes the OTHER buffer,
        // and the single barrier below (top of next iter) orders it.
    }

    const int col0 = bn * 128 + tc * 8;
    float bb[8];
#pragma unroll
    for (int j = 0; j < 8; ++j) bb[j] = bc1[col0 + j];
#pragma unroll
    for (int i = 0; i < 4; ++i) {
        const int row = bm * 64 + tr * 4 + i;
        float o[8];
#pragma unroll
        for (int j = 0; j < 8; ++j) {
            float v = acc[i][j] + bb[j];
            o[j] = 0.5f * v * (1.0f + erff(v * 0.70710678118654752440f));
        }
        float* dst = h + (size_t)row * HD4 + col0;
        *(float4*)(dst)     = *(float4*)&o[0];
        *(float4*)(dst + 4) = *(float4*)&o[4];
    }
}

// ---------------------------------------------------------------------------
// Kernel 2: conf[n] = sigmoid(h[n,:] . Wc2 + bc2), one wave per row
// ---------------------------------------------------------------------------
__global__ __launch_bounds__(256) void conf_reduce_kernel(
    const float* __restrict__ h, const float* __restrict__ Wc2,
    const float* __restrict__ bc2, float* __restrict__ conf)
{
    const int wv = threadIdx.x >> 6, lane = threadIdx.x & 63;
    const int n = blockIdx.x * 4 + wv;
    const float* hr = h + (size_t)n * HD4;
    float s = 0.0f;
#pragma unroll
    for (int t = 0; t < 2; ++t) {
        const int j = t * 256 + lane * 4;
        float4 hv = *(const float4*)(hr + j);
        float4 w4 = *(const float4*)(Wc2 + j);
        s = fmaf(hv.x, w4.x, s);
        s = fmaf(hv.y, w4.y, s);
        s = fmaf(hv.z, w4.z, s);
        s = fmaf(hv.w, w4.w, s);
    }
#pragma unroll
    for (int m = 32; m; m >>= 1) s += __shfl_xor(s, m, 64);
    if (lane == 0) {
        float v = s + bc2[0];
        conf[n] = 1.0f / (1.0f + expf(-v));
    }
}

// ---------------------------------------------------------------------------
// Kernel 3: El partials = x @ We_flat over K-chunk ks (K-split=4 for occupancy:
// grid (256,4) = 1024 blocks = 4/CU, was 256 = 1/CU).
// BM=64, BN=64, BK=16, 256 threads, 4x4 microtile, two-level K accumulation.
// Writes Elp[ks][row][64]; reduce_el sums chunks in fixed ascending order.
// ---------------------------------------------------------------------------
__global__ __launch_bounds__(256) void gemm_experts_kernel(
    const float* __restrict__ x, const float* __restrict__ We,
    float* __restrict__ Elp)
{
    __shared__ float As[16][68];
    __shared__ float Bs[16][68];
    const int tid = threadIdx.x;
    const int bm = blockIdx.x;      // 0..255
    const int ks = blockIdx.y;      // 0..3 K-chunk
    const int tr = tid >> 4, tc = tid & 15;

    float acc[4][4];
#pragma unroll
    for (int i = 0; i < 4; ++i)
#pragma unroll
        for (int j = 0; j < 4; ++j) acc[i][j] = 0.0f;

    const float* xb = x + (size_t)bm * 64 * HDIM;
    const int arow = tid >> 2, ak4 = tid & 3;
    const int bkk = tid >> 4;            // k-row 0..15
    const int bgrp = (tid >> 2) & 3;     // group 0..3
    const int be4 = tid & 3;             // e-quad 0..3

    const int kbeg = ks * (HDIM / KSPLIT);
    const int kend = kbeg + (HDIM / KSPLIT);
    for (int k0 = kbeg; k0 < kend; k0 += 16) {
        float4 va = *(const float4*)(xb + (size_t)arow * HDIM + k0 + ak4 * 4);
        As[ak4 * 4 + 0][arow] = va.x;
        As[ak4 * 4 + 1][arow] = va.y;
        As[ak4 * 4 + 2][arow] = va.z;
        As[ak4 * 4 + 3][arow] = va.w;
        // We[g][k][e] -> Bs[k][g*16+e]
        *(float4*)&Bs[bkk][bgrp * 16 + be4 * 4] =
            *(const float4*)(We + (size_t)bgrp * HDIM * EPG
                             + (size_t)(k0 + bkk) * EPG + be4 * 4);
        __syncthreads();

        float acc_t[4][4];      // per-K-tile partial (reduces fp32 rounding drift)
#pragma unroll
        for (int i = 0; i < 4; ++i)
#pragma unroll
            for (int j = 0; j < 4; ++j) acc_t[i][j] = 0.0f;
#pragma unroll
        for (int k = 0; k < 16; ++k) {
            float av[4], bv[4];
            *(float4*)av = *(const float4*)&As[k][tr * 4];
            *(float4*)bv = *(const float4*)&Bs[k][tc * 4];
#pragma unroll
            for (int i = 0; i < 4; ++i)
#pragma unroll
                for (int j = 0; j < 4; ++j)
                    acc_t[i][j] = fmaf(av[i], bv[j], acc_t[i][j]);
        }
#pragma unroll
        for (int i = 0; i < 4; ++i)
#pragma unroll
            for (int j = 0; j < 4; ++j) acc[i][j] += acc_t[i][j];
        __syncthreads();
    }
#pragma unroll
    for (int i = 0; i < 4; ++i) {
        float o[4] = {acc[i][0], acc[i][1], acc[i][2], acc[i][3]};
        *(float4*)(Elp + ((size_t)ks * NTOK + bm * 64 + tr * 4 + i) * NE + tc * 4)
            = *(float4*)o;
    }
}

// ---------------------------------------------------------------------------
// Kernel 3b: El = sum over the 4 K-chunks (fixed ascending order, deterministic)
// ---------------------------------------------------------------------------
__global__ __launch_bounds__(256) void reduce_el_kernel(
    const float* __restrict__ Elp, float* __restrict__ El)
{
    const size_t i = ((size_t)blockIdx.x * 256 + threadIdx.x) * 4;
    float4 a = *(const float4*)(Elp + i);
    float4 b = *(const float4*)(Elp + (size_t)1 * NTOK * NE + i);
    float4 c = *(const float4*)(Elp + (size_t)2 * NTOK * NE + i);
    float4 d = *(const float4*)(Elp + (size_t)3 * NTOK * NE + i);
    float4 r;
    r.x = ((a.x + b.x) + c.x) + d.x;
    r.y = ((a.y + b.y) + c.y) + d.y;
    r.z = ((a.z + b.z) + c.z) + d.z;
    r.w = ((a.w + b.w) + c.w) + d.w;
    *(float4*)(El + i) = r;
}

// ---------------------------------------------------------------------------
// Kernel 4: Gl = x @ Wg   [16384x2048] @ [2048x4], one wave per row
// ---------------------------------------------------------------------------
__global__ __launch_bounds__(256) void gemv_gates_kernel(
    const float* __restrict__ x, const float* __restrict__ Wg,
    float* __restrict__ Gl)
{
    const int wv = threadIdx.x >> 6, lane = threadIdx.x & 63;
    const int n = blockIdx.x * 4 + wv;
    const float* xr = x + (size_t)n * HDIM;
    float a0 = 0, a1 = 0, a2 = 0, a3 = 0;
#pragma unroll
    for (int t = 0; t < 8; ++t) {
        const int k = t * 256 + lane * 4;
        float4 xv = *(const float4*)(xr + k);
        float4 w0 = *(const float4*)(Wg + (size_t)k * NG);
        float4 w1 = *(const float4*)(Wg + (size_t)k * NG + 4);
        float4 w2 = *(const float4*)(Wg + (size_t)k * NG + 8);
        float4 w3 = *(const float4*)(Wg + (size_t)k * NG + 12);
        a0 = fmaf(xv.x, w0.x, a0); a0 = fmaf(xv.y, w1.x, a0);
        a0 = fmaf(xv.z, w2.x, a0); a0 = fmaf(xv.w, w3.x, a0);
        a1 = fmaf(xv.x, w0.y, a1); a1 = fmaf(xv.y, w1.y, a1);
        a1 = fmaf(xv.z, w2.y, a1); a1 = fmaf(xv.w, w3.y, a1);
        a2 = fmaf(xv.x, w0.z, a2); a2 = fmaf(xv.y, w1.z, a2);
        a2 = fmaf(xv.z, w2.z, a2); a2 = fmaf(xv.w, w3.z, a2);
        a3 = fmaf(xv.x, w0.w, a3); a3 = fmaf(xv.y, w1.w, a3);
        a3 = fmaf(xv.z, w2.w, a3); a3 = fmaf(xv.w, w3.w, a3);
    }
#pragma unroll
    for (int m = 32; m; m >>= 1) {
        a0 += __shfl_xor(a0, m, 64);
        a1 += __shfl_xor(a1, m, 64);
        a2 += __shfl_xor(a2, m, 64);
        a3 += __shfl_xor(a3, m, 64);
    }
    if (lane == 0) {
        float4 r; r.x = a0; r.y = a1; r.z = a2; r.w = a3;
        *(float4*)(Gl + (size_t)n * NG) = r;
    }
}

// ---------------------------------------------------------------------------
// Kernel 5: per-token gating finalize. One thread per token. Unchanged.
// jax.lax.top_k tie-break = lowest index: strict-'>' scans from index 0.
// ---------------------------------------------------------------------------
__global__ __launch_bounds__(256) void finalize_kernel(
    const float* __restrict__ El, const float* __restrict__ Gl,
    const float* __restrict__ conf, const float* __restrict__ bgp,
    const float* __restrict__ bep, const float* __restrict__ prp,
    float* __restrict__ out)
{
    const int n = blockIdx.x * 256 + threadIdx.x;

    float gl0 = Gl[(size_t)n * NG + 0] + bgp[0];
    float gl1 = Gl[(size_t)n * NG + 1] + bgp[1];
    float gl2 = Gl[(size_t)n * NG + 2] + bgp[2];
    float gl3 = Gl[(size_t)n * NG + 3] + bgp[3];
    float gm = fmaxf(fmaxf(gl0, gl1), fmaxf(gl2, gl3));
    float e0 = expf(gl0 - gm), e1 = expf(gl1 - gm);
    float e2 = expf(gl2 - gm), e3 = expf(gl3 - gm);
    float gs = e0 + e1 + e2 + e3;
    float gp0 = e0 / gs, gp1 = e1 / gs, gp2 = e2 / gs, gp3 = e3 / gs;

    int g0 = 0; float t0 = gp0;
    if (gp1 > t0) { t0 = gp1; g0 = 1; }
    if (gp2 > t0) { t0 = gp2; g0 = 2; }
    if (gp3 > t0) { t0 = gp3; g0 = 3; }
    int g1 = -1; float t1 = -1.0f;
    if (g0 != 0)              { t1 = gp0; g1 = 0; }
    if (g0 != 1 && gp1 > t1)  { t1 = gp1; g1 = 1; }
    if (g0 != 2 && gp2 > t1)  { t1 = gp2; g1 = 2; }
    if (g0 != 3 && gp3 > t1)  { t1 = gp3; g1 = 3; }

    const float c = conf[n];
    const float uni = (1.0f - c) * (1.0f / 16.0f);

    int ci0, ci1, ci2, ci3;
    float cv0, cv1, cv2, cv3;

    auto proc = [&](int gid, float tp, int& ia, float& va, int& ib, float& vb) {
        const float* base = El + (size_t)n * NE + gid * EPG;
        const float* beb = bep + gid * EPG;
        const float* prb = prp + gid * EPG;
        float lv[16];
#pragma unroll
        for (int e = 0; e < 16; ++e) lv[e] = (base[e] + beb[e]) * prb[e];
        float m = lv[0];
#pragma unroll
        for (int e = 1; e < 16; ++e) m = fmaxf(m, lv[e]);
        float pe[16]; float s = 0.0f;
#pragma unroll
        for (int e = 0; e < 16; ++e) { pe[e] = expf(lv[e] - m); s += pe[e]; }
        const float cs = c / s;
        float bl[16];
#pragma unroll
        for (int e = 0; e < 16; ++e) bl[e] = fmaf(pe[e], cs, uni);
        int i0 = 0; float v0 = bl[0];
#pragma unroll
        for (int e = 1; e < 16; ++e) { if (bl[e] > v0) { v0 = bl[e]; i0 = e; } }
        int i1 = -1; float v1 = -1e30f;
#pragma unroll
        for (int e = 0; e < 16; ++e) {
            if (e != i0 && bl[e] > v1) { v1 = bl[e]; i1 = e; }
        }
        ia = gid * EPG + i0; va = v0 * tp;
        ib = gid * EPG + i1; vb = v1 * tp;
    };
    proc(g0, t0, ci0, cv0, ci1, cv1);
    proc(g1, t1, ci2, cv2, ci3, cv3);

    const float wsum = cv0 + cv1 + cv2 + cv3;
    const float winv = 1.0f / (wsum + 1e-9f);
    const float s0 = cv0 * winv, s1 = cv1 * winv;
    const float s2 = cv2 * winv, s3 = cv3 * winv;

    float bv = s0; int bi = ci0; int bslot = 0;
    if (s1 > bv || (s1 == bv && ci1 < bi)) { bv = s1; bi = ci1; bslot = 1; }
    if (s2 > bv || (s2 == bv && ci2 < bi)) { bv = s2; bi = ci2; bslot = 2; }
    if (s3 > bv || (s3 == bv && ci3 < bi)) { bv = s3; bi = ci3; bslot = 3; }
    float sv = -1.0f; int si = 1 << 30;
    if (bslot != 0 && (s0 > sv || (s0 == sv && ci0 < si))) { sv = s0; si = ci0; }
    if (bslot != 1 && (s1 > sv || (s1 == sv && ci1 < si))) { sv = s1; si = ci1; }
    if (bslot != 2 && (s2 > sv || (s2 == sv && ci2 < si))) { sv = s2; si = ci2; }
    if (bslot != 3 && (s3 > sv || (s3 == sv && ci3 < si))) { sv = s3; si = ci3; }

    float* d0 = out + (size_t)n * NE;
    float* d1 = out + (size_t)NTOK * NE + (size_t)n * NE;
#pragma unroll
    for (int q = 0; q < 16; ++q) {
        const int j = q * 4;
        float4 v;
        v.x = (j + 0 == bi) ? bv : ((j + 0 == si) ? sv : 0.0f);
        v.y = (j + 1 == bi) ? bv : ((j + 1 == si) ? sv : 0.0f);
        v.z = (j + 2 == bi) ? bv : ((j + 2 == si) ? sv : 0.0f);
        v.w = (j + 3 == bi) ? bv : ((j + 3 == si) ? sv : 0.0f);
        *(float4*)(d0 + j) = v;
        *(float4*)(d1 + j) = v;
    }
    if (n == 0) out[(size_t)2 * NTOK * NE] = 0.0f;   // aux_loss
}

// ---------------------------------------------------------------------------
extern "C" void kernel_launch(void* const* d_in, const int* in_sizes, int n_in,
                              void* d_out, int out_size, void* d_ws, size_t ws_size,
                              hipStream_t stream)
{
    const float* x    = (const float*)d_in[0];
    const float* Wg   = (const float*)d_in[1];
    const float* bg   = (const float*)d_in[2];
    const float* We   = (const float*)d_in[3];
    const float* be   = (const float*)d_in[4];
    const float* Wc1  = (const float*)d_in[5];
    const float* bc1  = (const float*)d_in[6];
    const float* Wc2  = (const float*)d_in[7];
    const float* bc2  = (const float*)d_in[8];
    const float* prio = (const float*)d_in[9];
    float* out = (float*)d_out;

    // ws layout (floats): h[NTOK*512] | conf[NTOK] | El[NTOK*64] | Gl[NTOK*4]
    // Elp (4*NTOK*64 = NTOK*256 floats) ALIASES h: h is dead after
    // conf_reduce, and gemm_experts launches after it on the same stream.
    float* h    = (float*)d_ws;
    float* conf = h + (size_t)NTOK * HD4;
    float* El   = conf + NTOK;
    float* Gl   = El + (size_t)NTOK * NE;
    float* Elp  = h;

    gemm_conf_kernel<<<dim3(NTOK / 64, HD4 / 128), 256, 0, stream>>>(x, Wc1, bc1, h);
    conf_reduce_kernel<<<NTOK / 4, 256, 0, stream>>>(h, Wc2, bc2, conf);
    gemm_experts_kernel<<<dim3(NTOK / 64, KSPLIT), 256, 0, stream>>>(x, We, Elp);
    reduce_el_kernel<<<(NTOK * NE / 4) / 256, 256, 0, stream>>>(Elp, El);
    gemv_gates_kernel<<<NTOK / 4, 256, 0, stream>>>(x, Wg, Gl);
    finalize_kernel<<<NTOK / 256, 256, 0, stream>>>(El, Gl, conf, bg, be, prio, out);
}

// Round 9
// 890.228 us; speedup vs baseline: 1.3538x; 1.3538x over previous
//
#include <hip/hip_runtime.h>

#define NTOK 16384
#define HDIM 2048
#define HD4  512
#define NG   4
#define EPG  16
#define NE   64
#define KSPLIT 4

// ---------------------------------------------------------------------------
// Kernel 1 (v3): h = gelu_exact(x @ Wc1 + bc1)  [16384x2048]@[2048x512]
// Wave = 16 rows x 512 cols; lane owns 8 UNIQUE cols (no B duplication).
//  - B: global, per-lane-unique 2xb128/k-step, 1-step register prefetch.
//    L1 return ~29 B/cyc < 64 peak; waves share lines via L1.
//  - A: block-staged LDS tile [32k x 64rows], read as 4xb128 BROADCAST
//    (wave-uniform addr, conflict-free). LDS pipe 192 cyc < VALU 256/k-step.
//  - 128 FMA/lane/k-step -> VALU-bound. 4 waves/CU, ILP-based hiding.
//  - acc order per element = sequential k=0..2047 (bit-identical to r5 PASS).
// ---------------------------------------------------------------------------
__global__ __launch_bounds__(256) void gemm_conf_kernel(
    const float* __restrict__ x, const float* __restrict__ Wc1,
    const float* __restrict__ bc1, float* __restrict__ h)
{
    __shared__ float Asm[2][32][68];      // [buf][kk][local row], stride 68 (16B-aligned, 544B%128B spreads banks)
    const int tid  = threadIdx.x;
    const int bm   = blockIdx.x;          // 0..255 : rows bm*64..+63
    const int w    = tid >> 6;            // wave 0..3
    const int lane = tid & 63;
    const int rbase = w * 16;             // this wave's local row base
    const int col   = lane * 8;           // this lane's global col base

    // staging: thread t loads rows srow, k-window skq*8..+7 (128B per 4-thread group)
    const int srow = tid >> 2;            // 0..63
    const int skq  = tid & 3;             // 0..3
    const float* xsrc = x + (size_t)(bm * 64 + srow) * HDIM + skq * 8;

    float acc[16][8];
#pragma unroll
    for (int r = 0; r < 16; ++r)
#pragma unroll
        for (int j = 0; j < 8; ++j) acc[r][j] = 0.0f;

    // prologue: stage k-tile 0
    {
        float4 s0 = *(const float4*)(xsrc);
        float4 s1 = *(const float4*)(xsrc + 4);
        const int kk = skq * 8;
        Asm[0][kk + 0][srow] = s0.x;
        Asm[0][kk + 1][srow] = s0.y;
        Asm[0][kk + 2][srow] = s0.z;
        Asm[0][kk + 3][srow] = s0.w;
        Asm[0][kk + 4][srow] = s1.x;
        Asm[0][kk + 5][srow] = s1.y;
        Asm[0][kk + 6][srow] = s1.z;
        Asm[0][kk + 7][srow] = s1.w;
    }
    __syncthreads();

    const float* wb = Wc1 + col;          // col stride: row-major [2048][512]
    int cur = 0;

    for (int t = 0; t < HDIM / 32; ++t) {
        const int k0 = t * 32;
        // issue next A-tile global loads early (hidden under 32 k-steps)
        float4 n0, n1;
        const bool have_next = (t + 1 < HDIM / 32);
        if (have_next) {
            n0 = *(const float4*)(xsrc + (t + 1) * 32);
            n1 = *(const float4*)(xsrc + (t + 1) * 32 + 4);
        }

        const float* wk = wb + (size_t)k0 * HD4;
        float4 b0 = *(const float4*)(wk);
        float4 b1 = *(const float4*)(wk + 4);
#pragma unroll 8
        for (int kk = 0; kk < 32; ++kk) {
            // register-prefetch next k's B row
            const bool more = (k0 + kk + 1 < HDIM);
            float4 nb0, nb1;
            if (more) {
                nb0 = *(const float4*)(wk + HD4);
                nb1 = *(const float4*)(wk + HD4 + 4);
            }
            // A fragment: 16 rows, wave-uniform broadcast reads
            const float* ar = &Asm[cur][kk][rbase];
            float4 a0 = *(const float4*)(ar);
            float4 a1 = *(const float4*)(ar + 4);
            float4 a2 = *(const float4*)(ar + 8);
            float4 a3 = *(const float4*)(ar + 12);
            float av[16] = {a0.x, a0.y, a0.z, a0.w, a1.x, a1.y, a1.z, a1.w,
                            a2.x, a2.y, a2.z, a2.w, a3.x, a3.y, a3.z, a3.w};
            float bv[8]  = {b0.x, b0.y, b0.z, b0.w, b1.x, b1.y, b1.z, b1.w};
#pragma unroll
            for (int r = 0; r < 16; ++r)
#pragma unroll
                for (int j = 0; j < 8; ++j)
                    acc[r][j] = fmaf(av[r], bv[j], acc[r][j]);
            if (more) { b0 = nb0; b1 = nb1; }
            wk += HD4;
        }

        // write next A-tile into the other buffer, one barrier per tile
        if (have_next) {
            const int kk = skq * 8;
            const int nxt = cur ^ 1;
            Asm[nxt][kk + 0][srow] = n0.x;
            Asm[nxt][kk + 1][srow] = n0.y;
            Asm[nxt][kk + 2][srow] = n0.z;
            Asm[nxt][kk + 3][srow] = n0.w;
            Asm[nxt][kk + 4][srow] = n1.x;
            Asm[nxt][kk + 5][srow] = n1.y;
            Asm[nxt][kk + 6][srow] = n1.z;
            Asm[nxt][kk + 7][srow] = n1.w;
        }
        __syncthreads();
        cur ^= 1;
    }

    // epilogue: bias + exact GELU + store
    float bb[8];
#pragma unroll
    for (int j = 0; j < 8; ++j) bb[j] = bc1[col + j];
#pragma unroll
    for (int r = 0; r < 16; ++r) {
        const int row = bm * 64 + rbase + r;
        float o[8];
#pragma unroll
        for (int j = 0; j < 8; ++j) {
            float v = acc[r][j] + bb[j];
            o[j] = 0.5f * v * (1.0f + erff(v * 0.70710678118654752440f));
        }
        float* dst = h + (size_t)row * HD4 + col;
        *(float4*)(dst)     = *(float4*)&o[0];
        *(float4*)(dst + 4) = *(float4*)&o[4];
    }
}

// ---------------------------------------------------------------------------
// Kernel 2: conf[n] = sigmoid(h[n,:] . Wc2 + bc2), one wave per row
// ---------------------------------------------------------------------------
__global__ __launch_bounds__(256) void conf_reduce_kernel(
    const float* __restrict__ h, const float* __restrict__ Wc2,
    const float* __restrict__ bc2, float* __restrict__ conf)
{
    const int wv = threadIdx.x >> 6, lane = threadIdx.x & 63;
    const int n = blockIdx.x * 4 + wv;
    const float* hr = h + (size_t)n * HD4;
    float s = 0.0f;
#pragma unroll
    for (int t = 0; t < 2; ++t) {
        const int j = t * 256 + lane * 4;
        float4 hv = *(const float4*)(hr + j);
        float4 w4 = *(const float4*)(Wc2 + j);
        s = fmaf(hv.x, w4.x, s);
        s = fmaf(hv.y, w4.y, s);
        s = fmaf(hv.z, w4.z, s);
        s = fmaf(hv.w, w4.w, s);
    }
#pragma unroll
    for (int m = 32; m; m >>= 1) s += __shfl_xor(s, m, 64);
    if (lane == 0) {
        float v = s + bc2[0];
        conf[n] = 1.0f / (1.0f + expf(-v));
    }
}

// ---------------------------------------------------------------------------
// Kernel 3: El partials = x @ We_flat over K-chunk ks (K-split=4)
// ---------------------------------------------------------------------------
__global__ __launch_bounds__(256) void gemm_experts_kernel(
    const float* __restrict__ x, const float* __restrict__ We,
    float* __restrict__ Elp)
{
    __shared__ float As[16][68];
    __shared__ float Bs[16][68];
    const int tid = threadIdx.x;
    const int bm = blockIdx.x;      // 0..255
    const int ks = blockIdx.y;      // 0..3 K-chunk
    const int tr = tid >> 4, tc = tid & 15;

    float acc[4][4];
#pragma unroll
    for (int i = 0; i < 4; ++i)
#pragma unroll
        for (int j = 0; j < 4; ++j) acc[i][j] = 0.0f;

    const float* xb = x + (size_t)bm * 64 * HDIM;
    const int arow = tid >> 2, ak4 = tid & 3;
    const int bkk = tid >> 4;
    const int bgrp = (tid >> 2) & 3;
    const int be4 = tid & 3;

    const int kbeg = ks * (HDIM / KSPLIT);
    const int kend = kbeg + (HDIM / KSPLIT);
    for (int k0 = kbeg; k0 < kend; k0 += 16) {
        float4 va = *(const float4*)(xb + (size_t)arow * HDIM + k0 + ak4 * 4);
        As[ak4 * 4 + 0][arow] = va.x;
        As[ak4 * 4 + 1][arow] = va.y;
        As[ak4 * 4 + 2][arow] = va.z;
        As[ak4 * 4 + 3][arow] = va.w;
        *(float4*)&Bs[bkk][bgrp * 16 + be4 * 4] =
            *(const float4*)(We + (size_t)bgrp * HDIM * EPG
                             + (size_t)(k0 + bkk) * EPG + be4 * 4);
        __syncthreads();

        float acc_t[4][4];
#pragma unroll
        for (int i = 0; i < 4; ++i)
#pragma unroll
            for (int j = 0; j < 4; ++j) acc_t[i][j] = 0.0f;
#pragma unroll
        for (int k = 0; k < 16; ++k) {
            float av[4], bv[4];
            *(float4*)av = *(const float4*)&As[k][tr * 4];
            *(float4*)bv = *(const float4*)&Bs[k][tc * 4];
#pragma unroll
            for (int i = 0; i < 4; ++i)
#pragma unroll
                for (int j = 0; j < 4; ++j)
                    acc_t[i][j] = fmaf(av[i], bv[j], acc_t[i][j]);
        }
#pragma unroll
        for (int i = 0; i < 4; ++i)
#pragma unroll
            for (int j = 0; j < 4; ++j) acc[i][j] += acc_t[i][j];
        __syncthreads();
    }
#pragma unroll
    for (int i = 0; i < 4; ++i) {
        float o[4] = {acc[i][0], acc[i][1], acc[i][2], acc[i][3]};
        *(float4*)(Elp + ((size_t)ks * NTOK + bm * 64 + tr * 4 + i) * NE + tc * 4)
            = *(float4*)o;
    }
}

// ---------------------------------------------------------------------------
// Kernel 3b: El = sum over K-chunks (fixed order, deterministic)
// ---------------------------------------------------------------------------
__global__ __launch_bounds__(256) void reduce_el_kernel(
    const float* __restrict__ Elp, float* __restrict__ El)
{
    const size_t i = ((size_t)blockIdx.x * 256 + threadIdx.x) * 4;
    float4 a = *(const float4*)(Elp + i);
    float4 b = *(const float4*)(Elp + (size_t)1 * NTOK * NE + i);
    float4 c = *(const float4*)(Elp + (size_t)2 * NTOK * NE + i);
    float4 d = *(const float4*)(Elp + (size_t)3 * NTOK * NE + i);
    float4 r;
    r.x = ((a.x + b.x) + c.x) + d.x;
    r.y = ((a.y + b.y) + c.y) + d.y;
    r.z = ((a.z + b.z) + c.z) + d.z;
    r.w = ((a.w + b.w) + c.w) + d.w;
    *(float4*)(El + i) = r;
}

// ---------------------------------------------------------------------------
// Kernel 4: Gl = x @ Wg, one wave per row
// ---------------------------------------------------------------------------
__global__ __launch_bounds__(256) void gemv_gates_kernel(
    const float* __restrict__ x, const float* __restrict__ Wg,
    float* __restrict__ Gl)
{
    const int wv = threadIdx.x >> 6, lane = threadIdx.x & 63;
    const int n = blockIdx.x * 4 + wv;
    const float* xr = x + (size_t)n * HDIM;
    float a0 = 0, a1 = 0, a2 = 0, a3 = 0;
#pragma unroll
    for (int t = 0; t < 8; ++t) {
        const int k = t * 256 + lane * 4;
        float4 xv = *(const float4*)(xr + k);
        float4 w0 = *(const float4*)(Wg + (size_t)k * NG);
        float4 w1 = *(const float4*)(Wg + (size_t)k * NG + 4);
        float4 w2 = *(const float4*)(Wg + (size_t)k * NG + 8);
        float4 w3 = *(const float4*)(Wg + (size_t)k * NG + 12);
        a0 = fmaf(xv.x, w0.x, a0); a0 = fmaf(xv.y, w1.x, a0);
        a0 = fmaf(xv.z, w2.x, a0); a0 = fmaf(xv.w, w3.x, a0);
        a1 = fmaf(xv.x, w0.y, a1); a1 = fmaf(xv.y, w1.y, a1);
        a1 = fmaf(xv.z, w2.y, a1); a1 = fmaf(xv.w, w3.y, a1);
        a2 = fmaf(xv.x, w0.z, a2); a2 = fmaf(xv.y, w1.z, a2);
        a2 = fmaf(xv.z, w2.z, a2); a2 = fmaf(xv.w, w3.z, a2);
        a3 = fmaf(xv.x, w0.w, a3); a3 = fmaf(xv.y, w1.w, a3);
        a3 = fmaf(xv.z, w2.w, a3); a3 = fmaf(xv.w, w3.w, a3);
    }
#pragma unroll
    for (int m = 32; m; m >>= 1) {
        a0 += __shfl_xor(a0, m, 64);
        a1 += __shfl_xor(a1, m, 64);
        a2 += __shfl_xor(a2, m, 64);
        a3 += __shfl_xor(a3, m, 64);
    }
    if (lane == 0) {
        float4 r; r.x = a0; r.y = a1; r.z = a2; r.w = a3;
        *(float4*)(Gl + (size_t)n * NG) = r;
    }
}

// ---------------------------------------------------------------------------
// Kernel 5: per-token gating finalize (unchanged; tie-break = lowest index)
// ---------------------------------------------------------------------------
__global__ __launch_bounds__(256) void finalize_kernel(
    const float* __restrict__ El, const float* __restrict__ Gl,
    const float* __restrict__ conf, const float* __restrict__ bgp,
    const float* __restrict__ bep, const float* __restrict__ prp,
    float* __restrict__ out)
{
    const int n = blockIdx.x * 256 + threadIdx.x;

    float gl0 = Gl[(size_t)n * NG + 0] + bgp[0];
    float gl1 = Gl[(size_t)n * NG + 1] + bgp[1];
    float gl2 = Gl[(size_t)n * NG + 2] + bgp[2];
    float gl3 = Gl[(size_t)n * NG + 3] + bgp[3];
    float gm = fmaxf(fmaxf(gl0, gl1), fmaxf(gl2, gl3));
    float e0 = expf(gl0 - gm), e1 = expf(gl1 - gm);
    float e2 = expf(gl2 - gm), e3 = expf(gl3 - gm);
    float gs = e0 + e1 + e2 + e3;
    float gp0 = e0 / gs, gp1 = e1 / gs, gp2 = e2 / gs, gp3 = e3 / gs;

    int g0 = 0; float t0 = gp0;
    if (gp1 > t0) { t0 = gp1; g0 = 1; }
    if (gp2 > t0) { t0 = gp2; g0 = 2; }
    if (gp3 > t0) { t0 = gp3; g0 = 3; }
    int g1 = -1; float t1 = -1.0f;
    if (g0 != 0)              { t1 = gp0; g1 = 0; }
    if (g0 != 1 && gp1 > t1)  { t1 = gp1; g1 = 1; }
    if (g0 != 2 && gp2 > t1)  { t1 = gp2; g1 = 2; }
    if (g0 != 3 && gp3 > t1)  { t1 = gp3; g1 = 3; }

    const float c = conf[n];
    const float uni = (1.0f - c) * (1.0f / 16.0f);

    int ci0, ci1, ci2, ci3;
    float cv0, cv1, cv2, cv3;

    auto proc = [&](int gid, float tp, int& ia, float& va, int& ib, float& vb) {
        const float* base = El + (size_t)n * NE + gid * EPG;
        const float* beb = bep + gid * EPG;
        const float* prb = prp + gid * EPG;
        float lv[16];
#pragma unroll
        for (int e = 0; e < 16; ++e) lv[e] = (base[e] + beb[e]) * prb[e];
        float m = lv[0];
#pragma unroll
        for (int e = 1; e < 16; ++e) m = fmaxf(m, lv[e]);
        float pe[16]; float s = 0.0f;
#pragma unroll
        for (int e = 0; e < 16; ++e) { pe[e] = expf(lv[e] - m); s += pe[e]; }
        const float cs = c / s;
        float bl[16];
#pragma unroll
        for (int e = 0; e < 16; ++e) bl[e] = fmaf(pe[e], cs, uni);
        int i0 = 0; float v0 = bl[0];
#pragma unroll
        for (int e = 1; e < 16; ++e) { if (bl[e] > v0) { v0 = bl[e]; i0 = e; } }
        int i1 = -1; float v1 = -1e30f;
#pragma unroll
        for (int e = 0; e < 16; ++e) {
            if (e != i0 && bl[e] > v1) { v1 = bl[e]; i1 = e; }
        }
        ia = gid * EPG + i0; va = v0 * tp;
        ib = gid * EPG + i1; vb = v1 * tp;
    };
    proc(g0, t0, ci0, cv0, ci1, cv1);
    proc(g1, t1, ci2, cv2, ci3, cv3);

    const float wsum = cv0 + cv1 + cv2 + cv3;
    const float winv = 1.0f / (wsum + 1e-9f);
    const float s0 = cv0 * winv, s1 = cv1 * winv;
    const float s2 = cv2 * winv, s3 = cv3 * winv;

    float bv = s0; int bi = ci0; int bslot = 0;
    if (s1 > bv || (s1 == bv && ci1 < bi)) { bv = s1; bi = ci1; bslot = 1; }
    if (s2 > bv || (s2 == bv && ci2 < bi)) { bv = s2; bi = ci2; bslot = 2; }
    if (s3 > bv || (s3 == bv && ci3 < bi)) { bv = s3; bi = ci3; bslot = 3; }
    float sv = -1.0f; int si = 1 << 30;
    if (bslot != 0 && (s0 > sv || (s0 == sv && ci0 < si))) { sv = s0; si = ci0; }
    if (bslot != 1 && (s1 > sv || (s1 == sv && ci1 < si))) { sv = s1; si = ci1; }
    if (bslot != 2 && (s2 > sv || (s2 == sv && ci2 < si))) { sv = s2; si = ci2; }
    if (bslot != 3 && (s3 > sv || (s3 == sv && ci3 < si))) { sv = s3; si = ci3; }

    float* d0 = out + (size_t)n * NE;
    float* d1 = out + (size_t)NTOK * NE + (size_t)n * NE;
#pragma unroll
    for (int q = 0; q < 16; ++q) {
        const int j = q * 4;
        float4 v;
        v.x = (j + 0 == bi) ? bv : ((j + 0 == si) ? sv : 0.0f);
        v.y = (j + 1 == bi) ? bv : ((j + 1 == si) ? sv : 0.0f);
        v.z = (j + 2 == bi) ? bv : ((j + 2 == si) ? sv : 0.0f);
        v.w = (j + 3 == bi) ? bv : ((j + 3 == si) ? sv : 0.0f);
        *(float4*)(d0 + j) = v;
        *(float4*)(d1 + j) = v;
    }
    if (n == 0) out[(size_t)2 * NTOK * NE] = 0.0f;   // aux_loss
}

// ---------------------------------------------------------------------------
extern "C" void kernel_launch(void* const* d_in, const int* in_sizes, int n_in,
                              void* d_out, int out_size, void* d_ws, size_t ws_size,
                              hipStream_t stream)
{
    const float* x    = (const float*)d_in[0];
    const float* Wg   = (const float*)d_in[1];
    const float* bg   = (const float*)d_in[2];
    const float* We   = (const float*)d_in[3];
    const float* be   = (const float*)d_in[4];
    const float* Wc1  = (const float*)d_in[5];
    const float* bc1  = (const float*)d_in[6];
    const float* Wc2  = (const float*)d_in[7];
    const float* bc2  = (const float*)d_in[8];
    const float* prio = (const float*)d_in[9];
    float* out = (float*)d_out;

    // ws layout (floats): h[NTOK*512] | conf[NTOK] | El[NTOK*64] | Gl[NTOK*4]
    // Elp (KSPLIT*NTOK*64) aliases h (dead after conf_reduce, stream-ordered).
    float* h    = (float*)d_ws;
    float* conf = h + (size_t)NTOK * HD4;
    float* El   = conf + NTOK;
    float* Gl   = El + (size_t)NTOK * NE;
    float* Elp  = h;

    gemm_conf_kernel<<<NTOK / 64, 256, 0, stream>>>(x, Wc1, bc1, h);
    conf_reduce_kernel<<<NTOK / 4, 256, 0, stream>>>(h, Wc2, bc2, conf);
    gemm_experts_kernel<<<dim3(NTOK / 64, KSPLIT), 256, 0, stream>>>(x, We, Elp);
    reduce_el_kernel<<<(NTOK * NE / 4) / 256, 256, 0, stream>>>(Elp, El);
    gemv_gates_kernel<<<NTOK / 4, 256, 0, stream>>>(x, Wg, Gl);
    finalize_kernel<<<NTOK / 256, 256, 0, stream>>>(El, Gl, conf, bg, be, prio, out);
}

// Round 12
// 856.871 us; speedup vs baseline: 1.4065x; 1.0389x over previous
//
#include <hip/hip_runtime.h>

#define NTOK 16384
#define HDIM 2048
#define HD4  512
#define NG   4
#define EPG  16
#define NE   64
#define KSPLIT 4

// ---------------------------------------------------------------------------
// Kernel 1 (v5): h = gelu_exact(x @ Wc1 + bc1)  [16384x2048]@[2048x512]
// 512 threads / 8 waves; wave = 8 rows x 512 cols -> 2 waves/SIMD (TLP).
// Lane owns cols {lane*4..+3} U {256+lane*4..+3}: bv = 2 contiguous
// ds_read_b128 (conflict-free). av = 2 wave-uniform broadcast b128.
// A+B LDS double-buffered, 1 barrier/tile, register prefetch of tile t+1.
// Staging maps (BUGFIX vs r10: derived for BK=16, all in-bounds):
//   A: tid<256, srow=tid>>2 (0..63), skq=tid&3, one float4 at k=skq*4.
//   B: all 512, kb=tid&15, sb=tid>>4 (0..31), 4 float4 at cols sb*16+q*4.
// acc order per element = sequential k=0..2047 (bit-identical to r9 PASS).
// ---------------------------------------------------------------------------
__global__ __launch_bounds__(512) void gemm_conf_kernel(
    const float* __restrict__ x, const float* __restrict__ Wc1,
    const float* __restrict__ bc1, float* __restrict__ h)
{
    __shared__ float Bs[2][16][516];   // pad 4: write banks spread, rows 16B-aligned
    __shared__ float As[2][16][68];
    const int tid  = threadIdx.x;      // 0..511
    const int bm   = blockIdx.x;       // 0..255
    const int w    = tid >> 6;         // 0..7
    const int lane = tid & 63;
    const int rbase = w * 8;
    const int c0 = lane * 4;
    const int c1 = 256 + lane * 4;

    const bool aStager = (tid < 256);
    const int srow = (tid & 255) >> 2; // 0..63 (valid when aStager)
    const int skq  = tid & 3;
    const float* xsrc = x + (size_t)(bm * 64 + srow) * HDIM + skq * 4;

    const int kb = tid & 15, sb = tid >> 4;   // sb 0..31
    const float* wsrc = Wc1 + (size_t)kb * HD4 + sb * 16;

    float acc[8][8];
#pragma unroll
    for (int r = 0; r < 8; ++r)
#pragma unroll
        for (int j = 0; j < 8; ++j) acc[r][j] = 0.0f;

    // prologue: tile 0 into regs
    float4 a0r = make_float4(0.f, 0.f, 0.f, 0.f);
    if (aStager) a0r = *(const float4*)(xsrc);
    float4 bbr[4];
#pragma unroll
    for (int q = 0; q < 4; ++q) bbr[q] = *(const float4*)(wsrc + q * 4);

    int cur = 0;
    const int NT = HDIM / 16;          // 128 tiles

    for (int t = 0; t < NT; ++t) {
        // write tile t (regs -> buf[cur])
        if (aStager) {
            const int kk = skq * 4;
            As[cur][kk + 0][srow] = a0r.x;
            As[cur][kk + 1][srow] = a0r.y;
            As[cur][kk + 2][srow] = a0r.z;
            As[cur][kk + 3][srow] = a0r.w;
        }
#pragma unroll
        for (int q = 0; q < 4; ++q)
            *(float4*)&Bs[cur][kb][sb * 16 + q * 4] = bbr[q];
        // issue tile t+1 global loads (hidden under barrier+compute)
        if (t + 1 < NT) {
            if (aStager) a0r = *(const float4*)(xsrc + (t + 1) * 16);
            const float* wn = wsrc + (size_t)(t + 1) * 16 * HD4;
#pragma unroll
            for (int q = 0; q < 4; ++q) bbr[q] = *(const float4*)(wn + q * 4);
        }
        __syncthreads();

        // compute tile from buf[cur] with next-k register prefetch
        float4 av0 = *(const float4*)&As[cur][0][rbase];
        float4 av1 = *(const float4*)&As[cur][0][rbase + 4];
        float4 bv0 = *(const float4*)&Bs[cur][0][c0];
        float4 bv1 = *(const float4*)&Bs[cur][0][c1];
#pragma unroll
        for (int kk = 0; kk < 16; ++kk) {
            float4 na0, na1, nb0, nb1;
            if (kk < 15) {
                na0 = *(const float4*)&As[cur][kk + 1][rbase];
                na1 = *(const float4*)&As[cur][kk + 1][rbase + 4];
                nb0 = *(const float4*)&Bs[cur][kk + 1][c0];
                nb1 = *(const float4*)&Bs[cur][kk + 1][c1];
            }
            float av[8] = {av0.x, av0.y, av0.z, av0.w, av1.x, av1.y, av1.z, av1.w};
            float bv[8] = {bv0.x, bv0.y, bv0.z, bv0.w, bv1.x, bv1.y, bv1.z, bv1.w};
#pragma unroll
            for (int r = 0; r < 8; ++r)
#pragma unroll
                for (int j = 0; j < 8; ++j)
                    acc[r][j] = fmaf(av[r], bv[j], acc[r][j]);
            if (kk < 15) { av0 = na0; av1 = na1; bv0 = nb0; bv1 = nb1; }
        }
        cur ^= 1;
        // single barrier/tile: next iteration writes the OTHER buffer; a wave
        // can only be one iteration ahead of any reader (barrier-ordered).
    }

    // epilogue: bias + exact GELU + store
    float4 bq0 = *(const float4*)(bc1 + c0);
    float4 bq1 = *(const float4*)(bc1 + c1);
    float bb[8] = {bq0.x, bq0.y, bq0.z, bq0.w, bq1.x, bq1.y, bq1.z, bq1.w};
#pragma unroll
    for (int r = 0; r < 8; ++r) {
        const int row = bm * 64 + rbase + r;
        float o[8];
#pragma unroll
        for (int j = 0; j < 8; ++j) {
            float v = acc[r][j] + bb[j];
            o[j] = 0.5f * v * (1.0f + erff(v * 0.70710678118654752440f));
        }
        float* dst = h + (size_t)row * HD4;
        *(float4*)(dst + c0) = *(float4*)&o[0];
        *(float4*)(dst + c1) = *(float4*)&o[4];
    }
}

// ---------------------------------------------------------------------------
// Kernel 2: conf[n] = sigmoid(h[n,:] . Wc2 + bc2), one wave per row
// ---------------------------------------------------------------------------
__global__ __launch_bounds__(256) void conf_reduce_kernel(
    const float* __restrict__ h, const float* __restrict__ Wc2,
    const float* __restrict__ bc2, float* __restrict__ conf)
{
    const int wv = threadIdx.x >> 6, lane = threadIdx.x & 63;
    const int n = blockIdx.x * 4 + wv;
    const float* hr = h + (size_t)n * HD4;
    float s = 0.0f;
#pragma unroll
    for (int t = 0; t < 2; ++t) {
        const int j = t * 256 + lane * 4;
        float4 hv = *(const float4*)(hr + j);
        float4 w4 = *(const float4*)(Wc2 + j);
        s = fmaf(hv.x, w4.x, s);
        s = fmaf(hv.y, w4.y, s);
        s = fmaf(hv.z, w4.z, s);
        s = fmaf(hv.w, w4.w, s);
    }
#pragma unroll
    for (int m = 32; m; m >>= 1) s += __shfl_xor(s, m, 64);
    if (lane == 0) {
        float v = s + bc2[0];
        conf[n] = 1.0f / (1.0f + expf(-v));
    }
}

// ---------------------------------------------------------------------------
// Kernel 3: El partials = x @ We_flat over K-chunk ks (K-split=4)
// ---------------------------------------------------------------------------
__global__ __launch_bounds__(256) void gemm_experts_kernel(
    const float* __restrict__ x, const float* __restrict__ We,
    float* __restrict__ Elp)
{
    __shared__ float As[16][68];
    __shared__ float Bs[16][68];
    const int tid = threadIdx.x;
    const int bm = blockIdx.x;      // 0..255
    const int ks = blockIdx.y;      // 0..3 K-chunk
    const int tr = tid >> 4, tc = tid & 15;

    float acc[4][4];
#pragma unroll
    for (int i = 0; i < 4; ++i)
#pragma unroll
        for (int j = 0; j < 4; ++j) acc[i][j] = 0.0f;

    const float* xb = x + (size_t)bm * 64 * HDIM;
    const int arow = tid >> 2, ak4 = tid & 3;
    const int bkk = tid >> 4;
    const int bgrp = (tid >> 2) & 3;
    const int be4 = tid & 3;

    const int kbeg = ks * (HDIM / KSPLIT);
    const int kend = kbeg + (HDIM / KSPLIT);
    for (int k0 = kbeg; k0 < kend; k0 += 16) {
        float4 va = *(const float4*)(xb + (size_t)arow * HDIM + k0 + ak4 * 4);
        As[ak4 * 4 + 0][arow] = va.x;
        As[ak4 * 4 + 1][arow] = va.y;
        As[ak4 * 4 + 2][arow] = va.z;
        As[ak4 * 4 + 3][arow] = va.w;
        *(float4*)&Bs[bkk][bgrp * 16 + be4 * 4] =
            *(const float4*)(We + (size_t)bgrp * HDIM * EPG
                             + (size_t)(k0 + bkk) * EPG + be4 * 4);
        __syncthreads();

        float acc_t[4][4];
#pragma unroll
        for (int i = 0; i < 4; ++i)
#pragma unroll
            for (int j = 0; j < 4; ++j) acc_t[i][j] = 0.0f;
#pragma unroll
        for (int k = 0; k < 16; ++k) {
            float av[4], bv[4];
            *(float4*)av = *(const float4*)&As[k][tr * 4];
            *(float4*)bv = *(const float4*)&Bs[k][tc * 4];
#pragma unroll
            for (int i = 0; i < 4; ++i)
#pragma unroll
                for (int j = 0; j < 4; ++j)
                    acc_t[i][j] = fmaf(av[i], bv[j], acc_t[i][j]);
        }
#pragma unroll
        for (int i = 0; i < 4; ++i)
#pragma unroll
            for (int j = 0; j < 4; ++j) acc[i][j] += acc_t[i][j];
        __syncthreads();
    }
#pragma unroll
    for (int i = 0; i < 4; ++i) {
        float o[4] = {acc[i][0], acc[i][1], acc[i][2], acc[i][3]};
        *(float4*)(Elp + ((size_t)ks * NTOK + bm * 64 + tr * 4 + i) * NE + tc * 4)
            = *(float4*)o;
    }
}

// ---------------------------------------------------------------------------
// Kernel 3b: El = sum over K-chunks (fixed order, deterministic)
// ---------------------------------------------------------------------------
__global__ __launch_bounds__(256) void reduce_el_kernel(
    const float* __restrict__ Elp, float* __restrict__ El)
{
    const size_t i = ((size_t)blockIdx.x * 256 + threadIdx.x) * 4;
    float4 a = *(const float4*)(Elp + i);
    float4 b = *(const float4*)(Elp + (size_t)1 * NTOK * NE + i);
    float4 c = *(const float4*)(Elp + (size_t)2 * NTOK * NE + i);
    float4 d = *(const float4*)(Elp + (size_t)3 * NTOK * NE + i);
    float4 r;
    r.x = ((a.x + b.x) + c.x) + d.x;
    r.y = ((a.y + b.y) + c.y) + d.y;
    r.z = ((a.z + b.z) + c.z) + d.z;
    r.w = ((a.w + b.w) + c.w) + d.w;
    *(float4*)(El + i) = r;
}

// ---------------------------------------------------------------------------
// Kernel 4: Gl = x @ Wg, one wave per row
// ---------------------------------------------------------------------------
__global__ __launch_bounds__(256) void gemv_gates_kernel(
    const float* __restrict__ x, const float* __restrict__ Wg,
    float* __restrict__ Gl)
{
    const int wv = threadIdx.x >> 6, lane = threadIdx.x & 63;
    const int n = blockIdx.x * 4 + wv;
    const float* xr = x + (size_t)n * HDIM;
    float a0 = 0, a1 = 0, a2 = 0, a3 = 0;
#pragma unroll
    for (int t = 0; t < 8; ++t) {
        const int k = t * 256 + lane * 4;
        float4 xv = *(const float4*)(xr + k);
        float4 w0 = *(const float4*)(Wg + (size_t)k * NG);
        float4 w1 = *(const float4*)(Wg + (size_t)k * NG + 4);
        float4 w2 = *(const float4*)(Wg + (size_t)k * NG + 8);
        float4 w3 = *(const float4*)(Wg + (size_t)k * NG + 12);
        a0 = fmaf(xv.x, w0.x, a0); a0 = fmaf(xv.y, w1.x, a0);
        a0 = fmaf(xv.z, w2.x, a0); a0 = fmaf(xv.w, w3.x, a0);
        a1 = fmaf(xv.x, w0.y, a1); a1 = fmaf(xv.y, w1.y, a1);
        a1 = fmaf(xv.z, w2.y, a1); a1 = fmaf(xv.w, w3.y, a1);
        a2 = fmaf(xv.x, w0.z, a2); a2 = fmaf(xv.y, w1.z, a2);
        a2 = fmaf(xv.z, w2.z, a2); a2 = fmaf(xv.w, w3.z, a2);
        a3 = fmaf(xv.x, w0.w, a3); a3 = fmaf(xv.y, w1.w, a3);
        a3 = fmaf(xv.z, w2.w, a3); a3 = fmaf(xv.w, w3.w, a3);
    }
#pragma unroll
    for (int m = 32; m; m >>= 1) {
        a0 += __shfl_xor(a0, m, 64);
        a1 += __shfl_xor(a1, m, 64);
        a2 += __shfl_xor(a2, m, 64);
        a3 += __shfl_xor(a3, m, 64);
    }
    if (lane == 0) {
        float4 r; r.x = a0; r.y = a1; r.z = a2; r.w = a3;
        *(float4*)(Gl + (size_t)n * NG) = r;
    }
}

// ---------------------------------------------------------------------------
// Kernel 5: per-token gating finalize (unchanged; tie-break = lowest index)
// ---------------------------------------------------------------------------
__global__ __launch_bounds__(256) void finalize_kernel(
    const float* __restrict__ El, const float* __restrict__ Gl,
    const float* __restrict__ conf, const float* __restrict__ bgp,
    const float* __restrict__ bep, const float* __restrict__ prp,
    float* __restrict__ out)
{
    const int n = blockIdx.x * 256 + threadIdx.x;

    float gl0 = Gl[(size_t)n * NG + 0] + bgp[0];
    float gl1 = Gl[(size_t)n * NG + 1] + bgp[1];
    float gl2 = Gl[(size_t)n * NG + 2] + bgp[2];
    float gl3 = Gl[(size_t)n * NG + 3] + bgp[3];
    float gm = fmaxf(fmaxf(gl0, gl1), fmaxf(gl2, gl3));
    float e0 = expf(gl0 - gm), e1 = expf(gl1 - gm);
    float e2 = expf(gl2 - gm), e3 = expf(gl3 - gm);
    float gs = e0 + e1 + e2 + e3;
    float gp0 = e0 / gs, gp1 = e1 / gs, gp2 = e2 / gs, gp3 = e3 / gs;

    int g0 = 0; float t0 = gp0;
    if (gp1 > t0) { t0 = gp1; g0 = 1; }
    if (gp2 > t0) { t0 = gp2; g0 = 2; }
    if (gp3 > t0) { t0 = gp3; g0 = 3; }
    int g1 = -1; float t1 = -1.0f;
    if (g0 != 0)              { t1 = gp0; g1 = 0; }
    if (g0 != 1 && gp1 > t1)  { t1 = gp1; g1 = 1; }
    if (g0 != 2 && gp2 > t1)  { t1 = gp2; g1 = 2; }
    if (g0 != 3 && gp3 > t1)  { t1 = gp3; g1 = 3; }

    const float c = conf[n];
    const float uni = (1.0f - c) * (1.0f / 16.0f);

    int ci0, ci1, ci2, ci3;
    float cv0, cv1, cv2, cv3;

    auto proc = [&](int gid, float tp, int& ia, float& va, int& ib, float& vb) {
        const float* base = El + (size_t)n * NE + gid * EPG;
        const float* beb = bep + gid * EPG;
        const float* prb = prp + gid * EPG;
        float lv[16];
#pragma unroll
        for (int e = 0; e < 16; ++e) lv[e] = (base[e] + beb[e]) * prb[e];
        float m = lv[0];
#pragma unroll
        for (int e = 1; e < 16; ++e) m = fmaxf(m, lv[e]);
        float pe[16]; float s = 0.0f;
#pragma unroll
        for (int e = 0; e < 16; ++e) { pe[e] = expf(lv[e] - m); s += pe[e]; }
        const float cs = c / s;
        float bl[16];
#pragma unroll
        for (int e = 0; e < 16; ++e) bl[e] = fmaf(pe[e], cs, uni);
        int i0 = 0; float v0 = bl[0];
#pragma unroll
        for (int e = 1; e < 16; ++e) { if (bl[e] > v0) { v0 = bl[e]; i0 = e; } }
        int i1 = -1; float v1 = -1e30f;
#pragma unroll
        for (int e = 0; e < 16; ++e) {
            if (e != i0 && bl[e] > v1) { v1 = bl[e]; i1 = e; }
        }
        ia = gid * EPG + i0; va = v0 * tp;
        ib = gid * EPG + i1; vb = v1 * tp;
    };
    proc(g0, t0, ci0, cv0, ci1, cv1);
    proc(g1, t1, ci2, cv2, ci3, cv3);

    const float wsum = cv0 + cv1 + cv2 + cv3;
    const float winv = 1.0f / (wsum + 1e-9f);
    const float s0 = cv0 * winv, s1 = cv1 * winv;
    const float s2 = cv2 * winv, s3 = cv3 * winv;

    float bv = s0; int bi = ci0; int bslot = 0;
    if (s1 > bv || (s1 == bv && ci1 < bi)) { bv = s1; bi = ci1; bslot = 1; }
    if (s2 > bv || (s2 == bv && ci2 < bi)) { bv = s2; bi = ci2; bslot = 2; }
    if (s3 > bv || (s3 == bv && ci3 < bi)) { bv = s3; bi = ci3; bslot = 3; }
    float sv = -1.0f; int si = 1 << 30;
    if (bslot != 0 && (s0 > sv || (s0 == sv && ci0 < si))) { sv = s0; si = ci0; }
    if (bslot != 1 && (s1 > sv || (s1 == sv && ci1 < si))) { sv = s1; si = ci1; }
    if (bslot != 2 && (s2 > sv || (s2 == sv && ci2 < si))) { sv = s2; si = ci2; }
    if (bslot != 3 && (s3 > sv || (s3 == sv && ci3 < si))) { sv = s3; si = ci3; }

    float* d0 = out + (size_t)n * NE;
    float* d1 = out + (size_t)NTOK * NE + (size_t)n * NE;
#pragma unroll
    for (int q = 0; q < 16; ++q) {
        const int j = q * 4;
        float4 v;
        v.x = (j + 0 == bi) ? bv : ((j + 0 == si) ? sv : 0.0f);
        v.y = (j + 1 == bi) ? bv : ((j + 1 == si) ? sv : 0.0f);
        v.z = (j + 2 == bi) ? bv : ((j + 2 == si) ? sv : 0.0f);
        v.w = (j + 3 == bi) ? bv : ((j + 3 == si) ? sv : 0.0f);
        *(float4*)(d0 + j) = v;
        *(float4*)(d1 + j) = v;
    }
    if (n == 0) out[(size_t)2 * NTOK * NE] = 0.0f;   // aux_loss
}

// ---------------------------------------------------------------------------
extern "C" void kernel_launch(void* const* d_in, const int* in_sizes, int n_in,
                              void* d_out, int out_size, void* d_ws, size_t ws_size,
                              hipStream_t stream)
{
    const float* x    = (const float*)d_in[0];
    const float* Wg   = (const float*)d_in[1];
    const float* bg   = (const float*)d_in[2];
    const float* We   = (const float*)d_in[3];
    const float* be   = (const float*)d_in[4];
    const float* Wc1  = (const float*)d_in[5];
    const float* bc1  = (const float*)d_in[6];
    const float* Wc2  = (const float*)d_in[7];
    const float* bc2  = (const float*)d_in[8];
    const float* prio = (const float*)d_in[9];
    float* out = (float*)d_out;

    // ws layout (floats): h[NTOK*512] | conf[NTOK] | El[NTOK*64] | Gl[NTOK*4]
    // Elp (KSPLIT*NTOK*64) aliases h (dead after conf_reduce, stream-ordered).
    float* h    = (float*)d_ws;
    float* conf = h + (size_t)NTOK * HD4;
    float* El   = conf + NTOK;
    float* Gl   = El + (size_t)NTOK * NE;
    float* Elp  = h;

    gemm_conf_kernel<<<NTOK / 64, 512, 0, stream>>>(x, Wc1, bc1, h);
    conf_reduce_kernel<<<NTOK / 4, 256, 0, stream>>>(h, Wc2, bc2, conf);
    gemm_experts_kernel<<<dim3(NTOK / 64, KSPLIT), 256, 0, stream>>>(x, We, Elp);
    reduce_el_kernel<<<(NTOK * NE / 4) / 256, 256, 0, stream>>>(Elp, El);
    gemv_gates_kernel<<<NTOK / 4, 256, 0, stream>>>(x, Wg, Gl);
    finalize_kernel<<<NTOK / 256, 256, 0, stream>>>(El, Gl, conf, bg, be, prio, out);
}

// Round 13
// 711.433 us; speedup vs baseline: 1.6940x; 1.2044x over previous
//
#include <hip/hip_runtime.h>

#define NTOK 16384
#define HDIM 2048
#define HD4  512
#define NG   4
#define EPG  16
#define NE   64
#define KSPLIT 4

// ---------------------------------------------------------------------------
// Kernel 1 (v6): h = gelu_exact(x @ Wc1 + bc1)  [16384x2048]@[2048x512]
// Grid (256,2): block = 64 rows x 256 cols, 512 thr / 8 waves -> 2 blocks/CU
// (42 KB LDS), 16 waves/CU to hide barrier/lgkm waits (v5 fix #2).
// Wave = 8 rows x 256 cols; lane owns 4 contiguous cols -> bv = ONE b128,
// full-width contiguous (ideal). av = 2 wave-uniform broadcast b128.
// NO manual kk-prefetch (v5 fix #1: the mov chains ate ~20% of issue slots);
// fully-unrolled direct ds_reads, compiler schedules lgkmcnt.
// acc order per element = sequential k=0..2047 (bit-identical to r12 PASS).
// ---------------------------------------------------------------------------
__global__ __launch_bounds__(512) void gemm_conf_kernel(
    const float* __restrict__ x, const float* __restrict__ Wc1,
    const float* __restrict__ bc1, float* __restrict__ h)
{
    __shared__ float Bs[2][16][260];   // [buf][kk][col in half], pad 4
    __shared__ float As[2][16][68];    // [buf][kk][row]
    const int tid  = threadIdx.x;      // 0..511
    const int bm   = blockIdx.x;       // 0..255 : rows bm*64..+63
    const int half = blockIdx.y;       // 0..1   : cols half*256..+255
    const int w    = tid >> 6;         // 0..7
    const int lane = tid & 63;
    const int rbase = w * 8;
    const int cb   = lane * 4;         // col-in-half base (contiguous lanes)

    const bool aStager = (tid < 256);
    const int srow = (tid & 255) >> 2; // 0..63
    const int skq  = tid & 3;          // float4 at k = skq*4 (covers k 0..15)
    const float* xsrc = x + (size_t)(bm * 64 + srow) * HDIM + skq * 4;

    const int kb = tid & 15, sb = tid >> 4;   // sb 0..31, 8 cols each
    const float* wsrc = Wc1 + (size_t)kb * HD4 + half * 256 + sb * 8;

    float acc[8][4];
#pragma unroll
    for (int r = 0; r < 8; ++r)
#pragma unroll
        for (int j = 0; j < 4; ++j) acc[r][j] = 0.0f;

    // prologue: tile 0 into regs
    float4 a0r = make_float4(0.f, 0.f, 0.f, 0.f);
    if (aStager) a0r = *(const float4*)(xsrc);
    float4 b0r = *(const float4*)(wsrc);
    float4 b1r = *(const float4*)(wsrc + 4);

    int cur = 0;
    const int NT = HDIM / 16;          // 128 tiles

    for (int t = 0; t < NT; ++t) {
        // write tile t (regs -> buf[cur])
        if (aStager) {
            const int kk = skq * 4;
            As[cur][kk + 0][srow] = a0r.x;
            As[cur][kk + 1][srow] = a0r.y;
            As[cur][kk + 2][srow] = a0r.z;
            As[cur][kk + 3][srow] = a0r.w;
        }
        *(float4*)&Bs[cur][kb][sb * 8]     = b0r;
        *(float4*)&Bs[cur][kb][sb * 8 + 4] = b1r;
        // issue tile t+1 global loads (hide under barrier+compute)
        if (t + 1 < NT) {
            if (aStager) a0r = *(const float4*)(xsrc + (t + 1) * 16);
            const float* wn = wsrc + (size_t)(t + 1) * 16 * HD4;
            b0r = *(const float4*)(wn);
            b1r = *(const float4*)(wn + 4);
        }
        __syncthreads();

        // compute tile from buf[cur]: direct reads, compiler-scheduled
#pragma unroll
        for (int kk = 0; kk < 16; ++kk) {
            float4 av0 = *(const float4*)&As[cur][kk][rbase];
            float4 av1 = *(const float4*)&As[cur][kk][rbase + 4];
            float4 bv  = *(const float4*)&Bs[cur][kk][cb];
            float av[8] = {av0.x, av0.y, av0.z, av0.w,
                           av1.x, av1.y, av1.z, av1.w};
#pragma unroll
            for (int r = 0; r < 8; ++r) {
                acc[r][0] = fmaf(av[r], bv.x, acc[r][0]);
                acc[r][1] = fmaf(av[r], bv.y, acc[r][1]);
                acc[r][2] = fmaf(av[r], bv.z, acc[r][2]);
                acc[r][3] = fmaf(av[r], bv.w, acc[r][3]);
            }
        }
        cur ^= 1;
        // single barrier/tile: next iteration writes the OTHER buffer; the
        // barrier at the top of iteration t+1 orders writes vs readers.
    }

    // epilogue: bias + exact GELU + store
    const int gcol = half * 256 + cb;
    float4 bq = *(const float4*)(bc1 + gcol);
    float bb[4] = {bq.x, bq.y, bq.z, bq.w};
#pragma unroll
    for (int r = 0; r < 8; ++r) {
        const int row = bm * 64 + rbase + r;
        float o[4];
#pragma unroll
        for (int j = 0; j < 4; ++j) {
            float v = acc[r][j] + bb[j];
            o[j] = 0.5f * v * (1.0f + erff(v * 0.70710678118654752440f));
        }
        *(float4*)(h + (size_t)row * HD4 + gcol) = *(float4*)&o[0];
    }
}

// ---------------------------------------------------------------------------
// Kernel 2: conf[n] = sigmoid(h[n,:] . Wc2 + bc2), one wave per row
// ---------------------------------------------------------------------------
__global__ __launch_bounds__(256) void conf_reduce_kernel(
    const float* __restrict__ h, const float* __restrict__ Wc2,
    const float* __restrict__ bc2, float* __restrict__ conf)
{
    const int wv = threadIdx.x >> 6, lane = threadIdx.x & 63;
    const int n = blockIdx.x * 4 + wv;
    const float* hr = h + (size_t)n * HD4;
    float s = 0.0f;
#pragma unroll
    for (int t = 0; t < 2; ++t) {
        const int j = t * 256 + lane * 4;
        float4 hv = *(const float4*)(hr + j);
        float4 w4 = *(const float4*)(Wc2 + j);
        s = fmaf(hv.x, w4.x, s);
        s = fmaf(hv.y, w4.y, s);
        s = fmaf(hv.z, w4.z, s);
        s = fmaf(hv.w, w4.w, s);
    }
#pragma unroll
    for (int m = 32; m; m >>= 1) s += __shfl_xor(s, m, 64);
    if (lane == 0) {
        float v = s + bc2[0];
        conf[n] = 1.0f / (1.0f + expf(-v));
    }
}

// ---------------------------------------------------------------------------
// Kernel 3: El partials = x @ We_flat over K-chunk ks (K-split=4)
// ---------------------------------------------------------------------------
__global__ __launch_bounds__(256) void gemm_experts_kernel(
    const float* __restrict__ x, const float* __restrict__ We,
    float* __restrict__ Elp)
{
    __shared__ float As[16][68];
    __shared__ float Bs[16][68];
    const int tid = threadIdx.x;
    const int bm = blockIdx.x;      // 0..255
    const int ks = blockIdx.y;      // 0..3 K-chunk
    const int tr = tid >> 4, tc = tid & 15;

    float acc[4][4];
#pragma unroll
    for (int i = 0; i < 4; ++i)
#pragma unroll
        for (int j = 0; j < 4; ++j) acc[i][j] = 0.0f;

    const float* xb = x + (size_t)bm * 64 * HDIM;
    const int arow = tid >> 2, ak4 = tid & 3;
    const int bkk = tid >> 4;
    const int bgrp = (tid >> 2) & 3;
    const int be4 = tid & 3;

    const int kbeg = ks * (HDIM / KSPLIT);
    const int kend = kbeg + (HDIM / KSPLIT);
    for (int k0 = kbeg; k0 < kend; k0 += 16) {
        float4 va = *(const float4*)(xb + (size_t)arow * HDIM + k0 + ak4 * 4);
        As[ak4 * 4 + 0][arow] = va.x;
        As[ak4 * 4 + 1][arow] = va.y;
        As[ak4 * 4 + 2][arow] = va.z;
        As[ak4 * 4 + 3][arow] = va.w;
        *(float4*)&Bs[bkk][bgrp * 16 + be4 * 4] =
            *(const float4*)(We + (size_t)bgrp * HDIM * EPG
                             + (size_t)(k0 + bkk) * EPG + be4 * 4);
        __syncthreads();

        float acc_t[4][4];
#pragma unroll
        for (int i = 0; i < 4; ++i)
#pragma unroll
            for (int j = 0; j < 4; ++j) acc_t[i][j] = 0.0f;
#pragma unroll
        for (int k = 0; k < 16; ++k) {
            float av[4], bv[4];
            *(float4*)av = *(const float4*)&As[k][tr * 4];
            *(float4*)bv = *(const float4*)&Bs[k][tc * 4];
#pragma unroll
            for (int i = 0; i < 4; ++i)
#pragma unroll
                for (int j = 0; j < 4; ++j)
                    acc_t[i][j] = fmaf(av[i], bv[j], acc_t[i][j]);
        }
#pragma unroll
        for (int i = 0; i < 4; ++i)
#pragma unroll
            for (int j = 0; j < 4; ++j) acc[i][j] += acc_t[i][j];
        __syncthreads();
    }
#pragma unroll
    for (int i = 0; i < 4; ++i) {
        float o[4] = {acc[i][0], acc[i][1], acc[i][2], acc[i][3]};
        *(float4*)(Elp + ((size_t)ks * NTOK + bm * 64 + tr * 4 + i) * NE + tc * 4)
            = *(float4*)o;
    }
}

// ---------------------------------------------------------------------------
// Kernel 3b: El = sum over K-chunks (fixed order, deterministic)
// ---------------------------------------------------------------------------
__global__ __launch_bounds__(256) void reduce_el_kernel(
    const float* __restrict__ Elp, float* __restrict__ El)
{
    const size_t i = ((size_t)blockIdx.x * 256 + threadIdx.x) * 4;
    float4 a = *(const float4*)(Elp + i);
    float4 b = *(const float4*)(Elp + (size_t)1 * NTOK * NE + i);
    float4 c = *(const float4*)(Elp + (size_t)2 * NTOK * NE + i);
    float4 d = *(const float4*)(Elp + (size_t)3 * NTOK * NE + i);
    float4 r;
    r.x = ((a.x + b.x) + c.x) + d.x;
    r.y = ((a.y + b.y) + c.y) + d.y;
    r.z = ((a.z + b.z) + c.z) + d.z;
    r.w = ((a.w + b.w) + c.w) + d.w;
    *(float4*)(El + i) = r;
}

// ---------------------------------------------------------------------------
// Kernel 4: Gl = x @ Wg, one wave per row
// ---------------------------------------------------------------------------
__global__ __launch_bounds__(256) void gemv_gates_kernel(
    const float* __restrict__ x, const float* __restrict__ Wg,
    float* __restrict__ Gl)
{
    const int wv = threadIdx.x >> 6, lane = threadIdx.x & 63;
    const int n = blockIdx.x * 4 + wv;
    const float* xr = x + (size_t)n * HDIM;
    float a0 = 0, a1 = 0, a2 = 0, a3 = 0;
#pragma unroll
    for (int t = 0; t < 8; ++t) {
        const int k = t * 256 + lane * 4;
        float4 xv = *(const float4*)(xr + k);
        float4 w0 = *(const float4*)(Wg + (size_t)k * NG);
        float4 w1 = *(const float4*)(Wg + (size_t)k * NG + 4);
        float4 w2 = *(const float4*)(Wg + (size_t)k * NG + 8);
        float4 w3 = *(const float4*)(Wg + (size_t)k * NG + 12);
        a0 = fmaf(xv.x, w0.x, a0); a0 = fmaf(xv.y, w1.x, a0);
        a0 = fmaf(xv.z, w2.x, a0); a0 = fmaf(xv.w, w3.x, a0);
        a1 = fmaf(xv.x, w0.y, a1); a1 = fmaf(xv.y, w1.y, a1);
        a1 = fmaf(xv.z, w2.y, a1); a1 = fmaf(xv.w, w3.y, a1);
        a2 = fmaf(xv.x, w0.z, a2); a2 = fmaf(xv.y, w1.z, a2);
        a2 = fmaf(xv.z, w2.z, a2); a2 = fmaf(xv.w, w3.z, a2);
        a3 = fmaf(xv.x, w0.w, a3); a3 = fmaf(xv.y, w1.w, a3);
        a3 = fmaf(xv.z, w2.w, a3); a3 = fmaf(xv.w, w3.w, a3);
    }
#pragma unroll
    for (int m = 32; m; m >>= 1) {
        a0 += __shfl_xor(a0, m, 64);
        a1 += __shfl_xor(a1, m, 64);
        a2 += __shfl_xor(a2, m, 64);
        a3 += __shfl_xor(a3, m, 64);
    }
    if (lane == 0) {
        float4 r; r.x = a0; r.y = a1; r.z = a2; r.w = a3;
        *(float4*)(Gl + (size_t)n * NG) = r;
    }
}

// ---------------------------------------------------------------------------
// Kernel 5: per-token gating finalize (unchanged; tie-break = lowest index)
// ---------------------------------------------------------------------------
__global__ __launch_bounds__(256) void finalize_kernel(
    const float* __restrict__ El, const float* __restrict__ Gl,
    const float* __restrict__ conf, const float* __restrict__ bgp,
    const float* __restrict__ bep, const float* __restrict__ prp,
    float* __restrict__ out)
{
    const int n = blockIdx.x * 256 + threadIdx.x;

    float gl0 = Gl[(size_t)n * NG + 0] + bgp[0];
    float gl1 = Gl[(size_t)n * NG + 1] + bgp[1];
    float gl2 = Gl[(size_t)n * NG + 2] + bgp[2];
    float gl3 = Gl[(size_t)n * NG + 3] + bgp[3];
    float gm = fmaxf(fmaxf(gl0, gl1), fmaxf(gl2, gl3));
    float e0 = expf(gl0 - gm), e1 = expf(gl1 - gm);
    float e2 = expf(gl2 - gm), e3 = expf(gl3 - gm);
    float gs = e0 + e1 + e2 + e3;
    float gp0 = e0 / gs, gp1 = e1 / gs, gp2 = e2 / gs, gp3 = e3 / gs;

    int g0 = 0; float t0 = gp0;
    if (gp1 > t0) { t0 = gp1; g0 = 1; }
    if (gp2 > t0) { t0 = gp2; g0 = 2; }
    if (gp3 > t0) { t0 = gp3; g0 = 3; }
    int g1 = -1; float t1 = -1.0f;
    if (g0 != 0)              { t1 = gp0; g1 = 0; }
    if (g0 != 1 && gp1 > t1)  { t1 = gp1; g1 = 1; }
    if (g0 != 2 && gp2 > t1)  { t1 = gp2; g1 = 2; }
    if (g0 != 3 && gp3 > t1)  { t1 = gp3; g1 = 3; }

    const float c = conf[n];
    const float uni = (1.0f - c) * (1.0f / 16.0f);

    int ci0, ci1, ci2, ci3;
    float cv0, cv1, cv2, cv3;

    auto proc = [&](int gid, float tp, int& ia, float& va, int& ib, float& vb) {
        const float* base = El + (size_t)n * NE + gid * EPG;
        const float* beb = bep + gid * EPG;
        const float* prb = prp + gid * EPG;
        float lv[16];
#pragma unroll
        for (int e = 0; e < 16; ++e) lv[e] = (base[e] + beb[e]) * prb[e];
        float m = lv[0];
#pragma unroll
        for (int e = 1; e < 16; ++e) m = fmaxf(m, lv[e]);
        float pe[16]; float s = 0.0f;
#pragma unroll
        for (int e = 0; e < 16; ++e) { pe[e] = expf(lv[e] - m); s += pe[e]; }
        const float cs = c / s;
        float bl[16];
#pragma unroll
        for (int e = 0; e < 16; ++e) bl[e] = fmaf(pe[e], cs, uni);
        int i0 = 0; float v0 = bl[0];
#pragma unroll
        for (int e = 1; e < 16; ++e) { if (bl[e] > v0) { v0 = bl[e]; i0 = e; } }
        int i1 = -1; float v1 = -1e30f;
#pragma unroll
        for (int e = 0; e < 16; ++e) {
            if (e != i0 && bl[e] > v1) { v1 = bl[e]; i1 = e; }
        }
        ia = gid * EPG + i0; va = v0 * tp;
        ib = gid * EPG + i1; vb = v1 * tp;
    };
    proc(g0, t0, ci0, cv0, ci1, cv1);
    proc(g1, t1, ci2, cv2, ci3, cv3);

    const float wsum = cv0 + cv1 + cv2 + cv3;
    const float winv = 1.0f / (wsum + 1e-9f);
    const float s0 = cv0 * winv, s1 = cv1 * winv;
    const float s2 = cv2 * winv, s3 = cv3 * winv;

    float bv = s0; int bi = ci0; int bslot = 0;
    if (s1 > bv || (s1 == bv && ci1 < bi)) { bv = s1; bi = ci1; bslot = 1; }
    if (s2 > bv || (s2 == bv && ci2 < bi)) { bv = s2; bi = ci2; bslot = 2; }
    if (s3 > bv || (s3 == bv && ci3 < bi)) { bv = s3; bi = ci3; bslot = 3; }
    float sv = -1.0f; int si = 1 << 30;
    if (bslot != 0 && (s0 > sv || (s0 == sv && ci0 < si))) { sv = s0; si = ci0; }
    if (bslot != 1 && (s1 > sv || (s1 == sv && ci1 < si))) { sv = s1; si = ci1; }
    if (bslot != 2 && (s2 > sv || (s2 == sv && ci2 < si))) { sv = s2; si = ci2; }
    if (bslot != 3 && (s3 > sv || (s3 == sv && ci3 < si))) { sv = s3; si = ci3; }

    float* d0 = out + (size_t)n * NE;
    float* d1 = out + (size_t)NTOK * NE + (size_t)n * NE;
#pragma unroll
    for (int q = 0; q < 16; ++q) {
        const int j = q * 4;
        float4 v;
        v.x = (j + 0 == bi) ? bv : ((j + 0 == si) ? sv : 0.0f);
        v.y = (j + 1 == bi) ? bv : ((j + 1 == si) ? sv : 0.0f);
        v.z = (j + 2 == bi) ? bv : ((j + 2 == si) ? sv : 0.0f);
        v.w = (j + 3 == bi) ? bv : ((j + 3 == si) ? sv : 0.0f);
        *(float4*)(d0 + j) = v;
        *(float4*)(d1 + j) = v;
    }
    if (n == 0) out[(size_t)2 * NTOK * NE] = 0.0f;   // aux_loss
}

// ---------------------------------------------------------------------------
extern "C" void kernel_launch(void* const* d_in, const int* in_sizes, int n_in,
                              void* d_out, int out_size, void* d_ws, size_t ws_size,
                              hipStream_t stream)
{
    const float* x    = (const float*)d_in[0];
    const float* Wg   = (const float*)d_in[1];
    const float* bg   = (const float*)d_in[2];
    const float* We   = (const float*)d_in[3];
    const float* be   = (const float*)d_in[4];
    const float* Wc1  = (const float*)d_in[5];
    const float* bc1  = (const float*)d_in[6];
    const float* Wc2  = (const float*)d_in[7];
    const float* bc2  = (const float*)d_in[8];
    const float* prio = (const float*)d_in[9];
    float* out = (float*)d_out;

    // ws layout (floats): h[NTOK*512] | conf[NTOK] | El[NTOK*64] | Gl[NTOK*4]
    // Elp (KSPLIT*NTOK*64) aliases h (dead after conf_reduce, stream-ordered).
    float* h    = (float*)d_ws;
    float* conf = h + (size_t)NTOK * HD4;
    float* El   = conf + NTOK;
    float* Gl   = El + (size_t)NTOK * NE;
    float* Elp  = h;

    gemm_conf_kernel<<<dim3(NTOK / 64, 2), 512, 0, stream>>>(x, Wc1, bc1, h);
    conf_reduce_kernel<<<NTOK / 4, 256, 0, stream>>>(h, Wc2, bc2, conf);
    gemm_experts_kernel<<<dim3(NTOK / 64, KSPLIT), 256, 0, stream>>>(x, We, Elp);
    reduce_el_kernel<<<(NTOK * NE / 4) / 256, 256, 0, stream>>>(Elp, El);
    gemv_gates_kernel<<<NTOK / 4, 256, 0, stream>>>(x, Wg, Gl);
    finalize_kernel<<<NTOK / 256, 256, 0, stream>>>(El, Gl, conf, bg, be, prio, out);
}